// Round 7
// baseline (373.480 us; speedup 1.0000x reference)
//
#include <hip/hip_runtime.h>
#include <math.h>

// Real grid (match reference): 421 x 421 E-grid, source at (210,210)
#define NXr 421
#define CXr 210
#define NSTEPS_C 200

// Temporal blocking round 7: block = 16x16 threads, each thread owns a 4x4
// cell quad -> EXT=64 halo-extended tile, Kt=20 fused steps (200 = 10 x 20),
// owned interior Bt = 64 - 2*20 = 24, max grid 18x18.
// Cost model from R3/R5/R6: per-dispatch overhead ~8-9 us dominates; this cuts
// dispatches 27 -> 12 at the price of (64/24)^2 = 7.1x halo redundancy, which
// support-gating keeps to ~50 us aggregate VALU.
#define Bt   24
#define Kt   20
#define EXT  64
#define SPITCH 66                  // even => float4-friendly LDS rows
#define NBLK 18                    // 18*24 = 432 computational domain
#define NPHASE (NSTEPS_C / Kt)     // 10

// Padded zero-ring layout: fields are PP x PP, computational domain [0,432)^2
// at offset (PAD,PAD). PAD=24 so block tiles (which overhang the owned region
// by Kt-? rows) stay inside [4,476) -- all hot I/O is unconditional float4.
// Coefficient tables are zero outside the real 421^2 domain, so cells outside
// it provably stay 0 forever.
#define PP   480
#define PAD  24
#define CP   (CXr + PAD)           // source in padded coords: 234
#define FSZ  (PP * PP)             // floats per padded field

struct PParams {
    float *aEz, *aEo, *aJz, *aJo, *aHx, *aHy;   // state set A
    float *bEz, *bEo, *bJz, *bJo, *bHx, *bHy;   // state set B
    const float *dexP, *deyP, *aexP, *aeyP, *ahxP, *ahyP;  // padded 1-D tables
    const float *C1a, *C2a, *Cbdxa, *Cbdya;
    const float *Caa, *Cba, *Cca, *Cda, *Cea, *dbhxa, *dbhya;
    const float *src;
};

// ---------------------------------------------------------------------------
// Init: zero both padded state sets; build padded coeff tables.
// dexP/deyP fold the interior mask (nonzero only for real coords 1..419).
// Zeroing BOTH sets every call keeps the support-gating skip exact.
// ---------------------------------------------------------------------------
__global__ void init_kernel(const float* __restrict__ sig_ex,
                            const float* __restrict__ sig_ey,
                            const float* __restrict__ sig_hx,
                            const float* __restrict__ sig_hy,
                            float de_fac, float dh_fac,
                            float* __restrict__ zero_base, int n_zero,
                            float* __restrict__ dexP, float* __restrict__ deyP,
                            float* __restrict__ aexP, float* __restrict__ aeyP,
                            float* __restrict__ ahxP, float* __restrict__ ahyP)
{
    int t = blockIdx.x * blockDim.x + threadIdx.x;
    int stride = gridDim.x * blockDim.x;
    for (int k = t; k < n_zero; k += stride) zero_base[k] = 0.0f;
    if (t < PP) {
        int g = t - PAD;
        dexP[t] = (g >= 1 && g <= NXr - 2) ? expf(-sig_ex[g] * de_fac) : 0.0f;
        deyP[t] = (g >= 1 && g <= NXr - 2) ? expf(-sig_ey[g] * de_fac) : 0.0f;
        aexP[t] = (g >= 0 && g <  NXr)     ? expf(-sig_ex[g] * dh_fac) : 0.0f;
        aeyP[t] = (g >= 0 && g <  NXr)     ? expf(-sig_ey[g] * dh_fac) : 0.0f;
        ahxP[t] = (g >= 0 && g <  NXr - 1) ? expf(-sig_hx[g] * dh_fac) : 0.0f;
        ahyP[t] = (g >= 0 && g <  NXr - 1) ? expf(-sig_hy[g] * dh_fac) : 0.0f;
    }
}

// ---------------------------------------------------------------------------
// One temporal-blocked phase (Kt=20 steps), ONE barrier per step.
// Ez is the only field exchanged through LDS (parity-double-buffered tile:
// step s+1 stores to the other buffer, so the single barrier is WAR-safe --
// structure verified in rounds 5/6). Up/left neighbor H values are ghost
// registers updated redundantly from the exchanged Ez (identical arithmetic
// to the neighbor's own update -> bit-exact).
// b0: host-computed active-region block offset (same for x and y).
// ---------------------------------------------------------------------------
__global__ __launch_bounds__(256, 2)
void phase_kernel(PParams p, int t, int b0)
{
    __shared__ __align__(16) float sEz[2][EXT][SPITCH];

    const int tid = threadIdx.x;
    const int tj = tid & 15, ti = tid >> 4;
    const int li0 = 4 * ti, lj0 = 4 * tj;
    // Tile anchor: block b's tile spans padded rows [b*24+4, b*24+68),
    // owned interior (li in [20,44)) = padded rows [b*24+24, b*24+48).
    const int r0 = ((int)blockIdx.x + b0) * Bt + (PAD - Kt) + li0;
    const int c0 = ((int)blockIdx.y + b0) * Bt + (PAD - Kt) + lj0;

    const float ca = p.Caa[0], cb = p.Cba[0], cc = p.Cca[0];
    const float cd = p.Cda[0], ce = p.Cea[0];
    const float ca1 = ca + 1.0f;
    const float C1 = p.C1a[0], C2 = p.C2a[0];
    const float cbdx = p.Cbdxa[0], cbdy = p.Cbdya[0];
    const float dbhx0 = p.dbhxa[0], dbhy0 = p.dbhya[0];

    // 1-D row/col damping factors (products formed on the fly to save VGPRs)
    float aexr[4], ahxr[4], dexr[4], aeyc[4], ahyc[4], deyc[4];
#pragma unroll
    for (int a = 0; a < 4; ++a) {
        aexr[a] = p.aexP[r0 + a];
        ahxr[a] = p.ahxP[r0 + a];
        dexr[a] = p.dexP[r0 + a];
        aeyc[a] = p.aeyP[c0 + a];
        ahyc[a] = p.ahyP[c0 + a];
        deyc[a] = p.deyP[c0 + a];
    }
    const float ahxU = p.ahxP[r0 - 1];   // r0-1 >= 3: always in-bounds
    const float ahyL = p.ahyP[c0 - 1];

    const bool odd = (t & 1) != 0;
    const float* cEz = odd ? p.bEz : p.aEz;
    const float* cEo = odd ? p.bEo : p.aEo;
    const float* cJz = odd ? p.bJz : p.aJz;
    const float* cJo = odd ? p.bJo : p.aJo;
    const float* cHx = odd ? p.bHx : p.aHx;
    const float* cHy = odd ? p.bHy : p.aHy;
    float* nEz = odd ? p.aEz : p.bEz;
    float* nEo = odd ? p.aEo : p.bEo;
    float* nJz = odd ? p.aJz : p.bJz;
    float* nJo = odd ? p.aJo : p.bJo;
    float* nHx = odd ? p.aHx : p.bHx;
    float* nHy = odd ? p.aHy : p.bHy;

    // Load 4x4 register state (unconditional padded float4; c0 % 4 == 0)
    float ez[4][4], eo[4][4], jz[4][4], jo[4][4], hx[4][4], hy[4][4];
#pragma unroll
    for (int a = 0; a < 4; ++a) {
        int g = (r0 + a) * PP + c0;
        float4 v;
        v = *(const float4*)&cEz[g]; ez[a][0]=v.x; ez[a][1]=v.y; ez[a][2]=v.z; ez[a][3]=v.w;
        v = *(const float4*)&cEo[g]; eo[a][0]=v.x; eo[a][1]=v.y; eo[a][2]=v.z; eo[a][3]=v.w;
        v = *(const float4*)&cJz[g]; jz[a][0]=v.x; jz[a][1]=v.y; jz[a][2]=v.z; jz[a][3]=v.w;
        v = *(const float4*)&cJo[g]; jo[a][0]=v.x; jo[a][1]=v.y; jo[a][2]=v.z; jo[a][3]=v.w;
        v = *(const float4*)&cHx[g]; hx[a][0]=v.x; hx[a][1]=v.y; hx[a][2]=v.z; hx[a][3]=v.w;
        v = *(const float4*)&cHy[g]; hy[a][0]=v.x; hy[a][1]=v.y; hy[a][2]=v.z; hy[a][3]=v.w;
    }
    // Ghost H (row above / col left of the quad)
    float hyU[4], hxL[4];
    {
        float4 v = *(const float4*)&cHy[(r0 - 1) * PP + c0];
        hyU[0]=v.x; hyU[1]=v.y; hyU[2]=v.z; hyU[3]=v.w;
#pragma unroll
        for (int a = 0; a < 4; ++a) hxL[a] = cHx[(r0 + a) * PP + c0 - 1];
    }

    const bool edgeR = (tj == 15), edgeD = (ti == 15);
    const bool edgeU = (ti == 0),  edgeL = (tj == 0);
    const int n0 = t * Kt;

    for (int s = 0; s < Kt; ++s) {
        float (*S)[SPITCH] = sEz[s & 1];
        // publish all 16 Ez cells (4 x float4 rows)
#pragma unroll
        for (int a = 0; a < 4; ++a)
            *(float4*)&S[li0 + a][lj0] =
                make_float4(ez[a][0], ez[a][1], ez[a][2], ez[a][3]);
        __syncthreads();

        // neighbor Ez from LDS
        float eR[4], eL[4];
#pragma unroll
        for (int a = 0; a < 4; ++a) {
            eR[a] = edgeR ? 0.0f : S[li0 + a][lj0 + 4];
            eL[a] = edgeL ? 0.0f : S[li0 + a][lj0 - 1];
        }
        float4 eD4 = edgeD ? make_float4(0.f,0.f,0.f,0.f)
                           : *(float4*)&S[li0 + 4][lj0];
        float4 eU4 = edgeU ? make_float4(0.f,0.f,0.f,0.f)
                           : *(float4*)&S[li0 - 1][lj0];
        float eD[4] = {eD4.x, eD4.y, eD4.z, eD4.w};
        float eU[4] = {eU4.x, eU4.y, eU4.z, eU4.w};

        // ---- H update (own 4x4) ----
#pragma unroll
        for (int a = 0; a < 4; ++a) {
#pragma unroll
            for (int b = 0; b < 3; ++b)
                hx[a][b] = aexr[a] * ahyc[b] *
                           (hx[a][b] - dbhx0 * (ez[a][b + 1] - ez[a][b]));
            hx[a][3] = aexr[a] * ahyc[3] *
                       (hx[a][3] - dbhx0 * (eR[a] - ez[a][3]));
        }
#pragma unroll
        for (int b = 0; b < 4; ++b) {
#pragma unroll
            for (int a = 0; a < 3; ++a)
                hy[a][b] = ahxr[a] * aeyc[b] *
                           (hy[a][b] + dbhy0 * (ez[a + 1][b] - ez[a][b]));
            hy[3][b] = ahxr[3] * aeyc[b] *
                       (hy[3][b] + dbhy0 * (eD[b] - ez[3][b]));
        }

        // ---- ghost H update (same arithmetic as neighbor's own) ----
#pragma unroll
        for (int b = 0; b < 4; ++b)
            hyU[b] = ahxU * aeyc[b] * (hyU[b] + dbhy0 * (ez[0][b] - eU[b]));
#pragma unroll
        for (int a = 0; a < 4; ++a)
            hxL[a] = aexr[a] * ahyL * (hxL[a] - dbhx0 * (ez[a][0] - eL[a]));

        // ---- E update (all operands in registers) ----
        float sv = p.src[n0 + s];
#pragma unroll
        for (int a = 0; a < 4; ++a)
#pragma unroll
            for (int b = 0; b < 4; ++b) {
                float cHyv = hy[a][b] - (a ? hy[a - 1][b] : hyU[b]);
                float cHxv = hx[a][b] - (b ? hx[a][b - 1] : hxL[a]);
                float e = ez[a][b], eold = eo[a][b];
                float j = jz[a][b], jold = jo[a][b];
                float phi = ca1 * j + cb * jold + cd * e + ce * eold;
                float en = (dexr[a] * deyc[b]) *
                    (C1 * e + cbdx * cHyv - cbdy * cHxv - C2 * phi);
                if (r0 + a == CP && c0 + b == CP) en += sv;  // src after mask*de
                float jn = phi - j + cc * en;   // == ca*j+cb*jo+cc*en+cd*e+ce*eo
                eo[a][b] = e;  ez[a][b] = en;
                jo[a][b] = j;  jz[a][b] = jn;
            }
        // Single barrier per step: next iteration stores to the OTHER LDS
        // buffer (parity), so late readers of this buffer are safe (R5/R6).
    }

    // store owned interior li,lj in [20,44) -> ti,tj in [5,11)
    if (ti >= 5 && ti < 11 && tj >= 5 && tj < 11) {
#pragma unroll
        for (int a = 0; a < 4; ++a) {
            int g = (r0 + a) * PP + c0;
            *(float4*)&nEz[g] = make_float4(ez[a][0], ez[a][1], ez[a][2], ez[a][3]);
            *(float4*)&nEo[g] = make_float4(eo[a][0], eo[a][1], eo[a][2], eo[a][3]);
            *(float4*)&nJz[g] = make_float4(jz[a][0], jz[a][1], jz[a][2], jz[a][3]);
            *(float4*)&nJo[g] = make_float4(jo[a][0], jo[a][1], jo[a][2], jo[a][3]);
            *(float4*)&nHx[g] = make_float4(hx[a][0], hx[a][1], hx[a][2], hx[a][3]);
            *(float4*)&nHy[g] = make_float4(hy[a][0], hy[a][1], hy[a][2], hy[a][3]);
        }
    }
}

// ---------------------------------------------------------------------------
// Copy padded Ez -> dense 421x421 output.
// ---------------------------------------------------------------------------
__global__ void copy_out_kernel(const float* __restrict__ ezP,
                                float* __restrict__ out)
{
    int idx = blockIdx.x * blockDim.x + threadIdx.x;
    if (idx >= NXr * NXr) return;
    int gi = idx / NXr, gj = idx - gi * NXr;
    out[idx] = ezP[(gi + PAD) * PP + (gj + PAD)];
}

// ---------------------------------------------------------------------------
extern "C" void kernel_launch(void* const* d_in, const int* in_sizes, int n_in,
                              void* d_out, int out_size, void* d_ws, size_t ws_size,
                              hipStream_t stream)
{
    const float* src    = (const float*)d_in[0];
    const float* C1     = (const float*)d_in[1];
    const float* C2     = (const float*)d_in[2];
    const float* Cb_dx  = (const float*)d_in[3];
    const float* Cb_dy  = (const float*)d_in[4];
    const float* dbhx   = (const float*)d_in[5];
    const float* dbhy   = (const float*)d_in[6];
    const float* Ca     = (const float*)d_in[7];
    const float* Cb     = (const float*)d_in[8];
    const float* Cc     = (const float*)d_in[9];
    const float* Cd     = (const float*)d_in[10];
    const float* Ce     = (const float*)d_in[11];
    const float* sig_ex = (const float*)d_in[12];
    const float* sig_ey = (const float*)d_in[13];
    const float* sig_hx = (const float*)d_in[14];
    const float* sig_hy = (const float*)d_in[15];
    // d_in[16] = n_steps (always 200) — hard-coded for graph capture.

    const double EPS0 = 1e-9 / 36.0 / M_PI;
    const double MU0  = 4.0 * M_PI * 1e-7;
    const double C0   = 1.0 / sqrt(MU0 * EPS0);
    const double DXd  = 2.5e-8, DYd = 2.5e-8;
    const double DT   = 0.99 / C0 / sqrt(1.0 / (DXd * DXd) + 1.0 / (DYd * DYd));
    const float de_fac = (float)(DT / EPS0);
    const float dh_fac = (float)(DT / MU0);

    // Workspace: [12 padded fields] [6 padded tables] (~11 MB, ws is 256 MB)
    float* fields = (float*)d_ws;
    float* w = fields + 12 * (size_t)FSZ;
    float* dexP = w; w += PP;
    float* deyP = w; w += PP;
    float* aexP = w; w += PP;
    float* aeyP = w; w += PP;
    float* ahxP = w; w += PP;
    float* ahyP = w; w += PP;

    PParams p;
    p.aEz = fields + 0 * (size_t)FSZ;  p.aEo = fields + 1 * (size_t)FSZ;
    p.aJz = fields + 2 * (size_t)FSZ;  p.aJo = fields + 3 * (size_t)FSZ;
    p.aHx = fields + 4 * (size_t)FSZ;  p.aHy = fields + 5 * (size_t)FSZ;
    p.bEz = fields + 6 * (size_t)FSZ;  p.bEo = fields + 7 * (size_t)FSZ;
    p.bJz = fields + 8 * (size_t)FSZ;  p.bJo = fields + 9 * (size_t)FSZ;
    p.bHx = fields + 10 * (size_t)FSZ; p.bHy = fields + 11 * (size_t)FSZ;
    p.dexP = dexP; p.deyP = deyP; p.aexP = aexP; p.aeyP = aeyP;
    p.ahxP = ahxP; p.ahyP = ahyP;
    p.C1a = C1; p.C2a = C2; p.Cbdxa = Cb_dx; p.Cbdya = Cb_dy;
    p.Caa = Ca; p.Cba = Cb; p.Cca = Cc; p.Cda = Cd; p.Cea = Ce;
    p.dbhxa = dbhx; p.dbhya = dbhy;
    p.src = src;

    init_kernel<<<512, 256, 0, stream>>>(sig_ex, sig_ey, sig_hx, sig_hy,
                                         de_fac, dh_fac,
                                         fields, 12 * FSZ,
                                         dexP, deyP, aexP, aeyP, ahxP, ahyP);

    dim3 blk(256);
    for (int t = 0; t < NPHASE; ++t) {
        // Support bound: after n steps the field is confined to a Chebyshev
        // ball of radius n-1 around the source. End of phase t is step
        // 20(t+1) -> radius 20t+19; +5 slack -> r = 20t+24. Launch blocks
        // whose TILE [b*24+4, b*24+68) intersects [CP-r, CP+r] (conservative
        // superset; extra blocks compute exact zeros). t-only formula ->
        // identical grid every call (graph-capture safe).
        int r  = 20 * t + 24;
        int lo = CP - r, hi = CP + r;
        int b0 = (lo - 68) / Bt; if (b0 < 0) b0 = 0;
        int b1 = (hi - 4) / Bt;  if (b1 > NBLK - 1) b1 = NBLK - 1;
        dim3 g(b1 - b0 + 1, b1 - b0 + 1);
        phase_kernel<<<g, blk, 0, stream>>>(p, t, b0);
    }

    // 10 phases: t=9 (odd) writes set A -> final Ez in aEz.
    copy_out_kernel<<<(NXr * NXr + 255) / 256, 256, 0, stream>>>(p.aEz,
                                                                 (float*)d_out);
}

// Round 8
// 313.583 us; speedup vs baseline: 1.1910x; 1.1910x over previous
//
#include <hip/hip_runtime.h>
#include <math.h>

// Real grid (match reference): 421 x 421 E-grid, source at (210,210)
#define NXr 421
#define CXr 210
#define NSTEPS_C 200

// Round 8: block = 16x16 threads x 4x4 cells -> EXT=64 tile, Kt=16 steps per
// phase (12 full phases + 1 tail of 8), owned interior Bt=32, grid <= 14x14 =
// 196 blocks <= 256 CUs. Since a 2nd resident block/CU is never needed,
// __launch_bounds__(256,1) lifts the VGPR cap to 512 -> no spill (the R7
// failure: 4x4 body at 256-VGPR cap spilled in the hot loop).
#define Bt   32
#define Kt   16
#define EXT  64
#define SPITCH 68                  // 68*4 B = 272 B row stride, 16B-aligned
#define NBLK 14                    // 14*32 = 448 >= 432 computational domain
#define NPHASE 13                  // 12 x 16 steps + 1 x 8 steps = 200

// Padded zero-ring layout: fields are PP x PP, domain at offset (PAD,PAD).
// Block b's tile spans padded rows [32b, 32b+64) (owned [32b+16, 32b+48)),
// max 13*32+64 = 480 = PP. Coefficient tables are zero outside the real 421^2
// domain, so outside cells provably stay 0 forever -> all hot I/O is
// unconditional float4. A zeroed guard row (PP floats) precedes the fields so
// ghost loads at padded row -1 are safe.
#define PP   480
#define PAD  16
#define CP   (CXr + PAD)           // source in padded coords: 226
#define FSZ  (PP * PP)             // floats per padded field

struct PParams {
    float *aEz, *aEo, *aJz, *aJo, *aHx, *aHy;   // state set A
    float *bEz, *bEo, *bJz, *bJo, *bHx, *bHy;   // state set B
    const float *dexP, *deyP, *aexP, *aeyP, *ahxP, *ahyP;  // padded 1-D tables
    const float *C1a, *C2a, *Cbdxa, *Cbdya;
    const float *Caa, *Cba, *Cca, *Cda, *Cea, *dbhxa, *dbhya;
    const float *src;
};

// ---------------------------------------------------------------------------
// Init: zero guard row + both padded state sets; build padded coeff tables.
// dexP/deyP fold the interior mask (nonzero only for real coords 1..419).
// Zeroing BOTH sets every call keeps the support-gating skip exact.
// ---------------------------------------------------------------------------
__global__ void init_kernel(const float* __restrict__ sig_ex,
                            const float* __restrict__ sig_ey,
                            const float* __restrict__ sig_hx,
                            const float* __restrict__ sig_hy,
                            float de_fac, float dh_fac,
                            float* __restrict__ zero_base, int n_zero,
                            float* __restrict__ dexP, float* __restrict__ deyP,
                            float* __restrict__ aexP, float* __restrict__ aeyP,
                            float* __restrict__ ahxP, float* __restrict__ ahyP)
{
    int t = blockIdx.x * blockDim.x + threadIdx.x;
    int stride = gridDim.x * blockDim.x;
    for (int k = t; k < n_zero; k += stride) zero_base[k] = 0.0f;
    if (t < PP) {
        int g = t - PAD;
        dexP[t] = (g >= 1 && g <= NXr - 2) ? expf(-sig_ex[g] * de_fac) : 0.0f;
        deyP[t] = (g >= 1 && g <= NXr - 2) ? expf(-sig_ey[g] * de_fac) : 0.0f;
        aexP[t] = (g >= 0 && g <  NXr)     ? expf(-sig_ex[g] * dh_fac) : 0.0f;
        aeyP[t] = (g >= 0 && g <  NXr)     ? expf(-sig_ey[g] * dh_fac) : 0.0f;
        ahxP[t] = (g >= 0 && g <  NXr - 1) ? expf(-sig_hx[g] * dh_fac) : 0.0f;
        ahyP[t] = (g >= 0 && g <  NXr - 1) ? expf(-sig_hy[g] * dh_fac) : 0.0f;
    }
}

// ---------------------------------------------------------------------------
// One temporal-blocked phase (`steps` <= 16), ONE barrier per step.
// Ez is the only field exchanged through LDS (parity-double-buffered tile:
// step s+1 stores to the other buffer -> single barrier is WAR-safe, verified
// R5/R6). Up/left neighbor H values are ghost registers updated redundantly
// from the exchanged Ez (identical arithmetic to the neighbor's own update).
// Validity induction (margin exactly tight for steps=16): E-state valid on
// [s, 64-s) at start of step s -> owned [16,48) exact after 16 steps.
// ---------------------------------------------------------------------------
__global__ __launch_bounds__(256, 1)
void phase_kernel(PParams p, int t, int b0, int steps, int n0)
{
    __shared__ __align__(16) float sEz[2][EXT][SPITCH];

    const int tid = threadIdx.x;
    const int tj = tid & 15, ti = tid >> 4;
    const int li0 = 4 * ti, lj0 = 4 * tj;
    const int r0 = ((int)blockIdx.x + b0) * Bt + li0;   // tile-local == padded-32b
    const int c0 = ((int)blockIdx.y + b0) * Bt + lj0;

    const float ca = p.Caa[0], cb = p.Cba[0], cc = p.Cca[0];
    const float cd = p.Cda[0], ce = p.Cea[0];
    const float ca1 = ca + 1.0f;
    const float C1 = p.C1a[0], C2 = p.C2a[0];
    const float cbdx = p.Cbdxa[0], cbdy = p.Cbdya[0];
    const float dbhx0 = p.dbhxa[0], dbhy0 = p.dbhya[0];

    // 1-D row/col damping factors (products formed on the fly)
    float aexr[4], ahxr[4], dexr[4], aeyc[4], ahyc[4], deyc[4];
#pragma unroll
    for (int a = 0; a < 4; ++a) {
        aexr[a] = p.aexP[r0 + a];
        ahxr[a] = p.ahxP[r0 + a];
        dexr[a] = p.dexP[r0 + a];
        aeyc[a] = p.aeyP[c0 + a];
        ahyc[a] = p.ahyP[c0 + a];
        deyc[a] = p.deyP[c0 + a];
    }
    const float ahxU = (r0 > 0) ? p.ahxP[r0 - 1] : 0.0f;
    const float ahyL = (c0 > 0) ? p.ahyP[c0 - 1] : 0.0f;

    const bool odd = (t & 1) != 0;
    const float* cEz = odd ? p.bEz : p.aEz;
    const float* cEo = odd ? p.bEo : p.aEo;
    const float* cJz = odd ? p.bJz : p.aJz;
    const float* cJo = odd ? p.bJo : p.aJo;
    const float* cHx = odd ? p.bHx : p.aHx;
    const float* cHy = odd ? p.bHy : p.aHy;
    float* nEz = odd ? p.aEz : p.bEz;
    float* nEo = odd ? p.aEo : p.bEo;
    float* nJz = odd ? p.aJz : p.bJz;
    float* nJo = odd ? p.aJo : p.bJo;
    float* nHx = odd ? p.aHx : p.bHx;
    float* nHy = odd ? p.aHy : p.bHy;

    // Load 4x4 register state (unconditional padded float4; c0 % 4 == 0)
    float ez[4][4], eo[4][4], jz[4][4], jo[4][4], hx[4][4], hy[4][4];
#pragma unroll
    for (int a = 0; a < 4; ++a) {
        int g = (r0 + a) * PP + c0;
        float4 v;
        v = *(const float4*)&cEz[g]; ez[a][0]=v.x; ez[a][1]=v.y; ez[a][2]=v.z; ez[a][3]=v.w;
        v = *(const float4*)&cEo[g]; eo[a][0]=v.x; eo[a][1]=v.y; eo[a][2]=v.z; eo[a][3]=v.w;
        v = *(const float4*)&cJz[g]; jz[a][0]=v.x; jz[a][1]=v.y; jz[a][2]=v.z; jz[a][3]=v.w;
        v = *(const float4*)&cJo[g]; jo[a][0]=v.x; jo[a][1]=v.y; jo[a][2]=v.z; jo[a][3]=v.w;
        v = *(const float4*)&cHx[g]; hx[a][0]=v.x; hx[a][1]=v.y; hx[a][2]=v.z; hx[a][3]=v.w;
        v = *(const float4*)&cHy[g]; hy[a][0]=v.x; hy[a][1]=v.y; hy[a][2]=v.z; hy[a][3]=v.w;
    }
    // Ghost H (row above / col left); guard row makes padded row -1 safe, and
    // col -1 lands in the previous row's far pad (always zero).
    float hyU[4], hxL[4];
    {
        float4 v = *(const float4*)&cHy[(r0 - 1) * PP + c0];
        hyU[0]=v.x; hyU[1]=v.y; hyU[2]=v.z; hyU[3]=v.w;
#pragma unroll
        for (int a = 0; a < 4; ++a) hxL[a] = cHx[(r0 + a) * PP + c0 - 1];
    }

    const bool edgeR = (tj == 15), edgeD = (ti == 15);
    const bool edgeU = (ti == 0),  edgeL = (tj == 0);

    for (int s = 0; s < steps; ++s) {
        float (*S)[SPITCH] = sEz[s & 1];
        // publish all 16 Ez cells (4 x float4 rows, 16B-aligned)
#pragma unroll
        for (int a = 0; a < 4; ++a)
            *(float4*)&S[li0 + a][lj0] =
                make_float4(ez[a][0], ez[a][1], ez[a][2], ez[a][3]);
        __syncthreads();

        // neighbor Ez from LDS
        float eR[4], eL[4];
#pragma unroll
        for (int a = 0; a < 4; ++a) {
            eR[a] = edgeR ? 0.0f : S[li0 + a][lj0 + 4];
            eL[a] = edgeL ? 0.0f : S[li0 + a][lj0 - 1];
        }
        float4 eD4 = edgeD ? make_float4(0.f,0.f,0.f,0.f)
                           : *(float4*)&S[li0 + 4][lj0];
        float4 eU4 = edgeU ? make_float4(0.f,0.f,0.f,0.f)
                           : *(float4*)&S[li0 - 1][lj0];
        float eD[4] = {eD4.x, eD4.y, eD4.z, eD4.w};
        float eU[4] = {eU4.x, eU4.y, eU4.z, eU4.w};

        // ---- H update (own 4x4) ----
#pragma unroll
        for (int a = 0; a < 4; ++a) {
#pragma unroll
            for (int b = 0; b < 3; ++b)
                hx[a][b] = aexr[a] * ahyc[b] *
                           (hx[a][b] - dbhx0 * (ez[a][b + 1] - ez[a][b]));
            hx[a][3] = aexr[a] * ahyc[3] *
                       (hx[a][3] - dbhx0 * (eR[a] - ez[a][3]));
        }
#pragma unroll
        for (int b = 0; b < 4; ++b) {
#pragma unroll
            for (int a = 0; a < 3; ++a)
                hy[a][b] = ahxr[a] * aeyc[b] *
                           (hy[a][b] + dbhy0 * (ez[a + 1][b] - ez[a][b]));
            hy[3][b] = ahxr[3] * aeyc[b] *
                       (hy[3][b] + dbhy0 * (eD[b] - ez[3][b]));
        }

        // ---- ghost H update (same arithmetic as neighbor's own) ----
#pragma unroll
        for (int b = 0; b < 4; ++b)
            hyU[b] = ahxU * aeyc[b] * (hyU[b] + dbhy0 * (ez[0][b] - eU[b]));
#pragma unroll
        for (int a = 0; a < 4; ++a)
            hxL[a] = aexr[a] * ahyL * (hxL[a] - dbhx0 * (ez[a][0] - eL[a]));

        // ---- E update (all operands in registers) ----
        float sv = p.src[n0 + s];
#pragma unroll
        for (int a = 0; a < 4; ++a)
#pragma unroll
            for (int b = 0; b < 4; ++b) {
                float cHyv = hy[a][b] - (a ? hy[a - 1][b] : hyU[b]);
                float cHxv = hx[a][b] - (b ? hx[a][b - 1] : hxL[a]);
                float e = ez[a][b], eold = eo[a][b];
                float j = jz[a][b], jold = jo[a][b];
                float phi = ca1 * j + cb * jold + cd * e + ce * eold;
                float en = (dexr[a] * deyc[b]) *
                    (C1 * e + cbdx * cHyv - cbdy * cHxv - C2 * phi);
                if (r0 + a == CP && c0 + b == CP) en += sv;  // src after mask*de
                float jn = phi - j + cc * en;   // == ca*j+cb*jo+cc*en+cd*e+ce*eo
                eo[a][b] = e;  ez[a][b] = en;
                jo[a][b] = j;  jz[a][b] = jn;
            }
        // Single barrier per step: next iteration stores to the OTHER LDS
        // buffer (parity), so late readers of this buffer are safe (R5/R6).
    }

    // store owned interior li in [16,48) -> ti,tj in [4,12)
    if (ti >= 4 && ti < 12 && tj >= 4 && tj < 12) {
#pragma unroll
        for (int a = 0; a < 4; ++a) {
            int g = (r0 + a) * PP + c0;
            *(float4*)&nEz[g] = make_float4(ez[a][0], ez[a][1], ez[a][2], ez[a][3]);
            *(float4*)&nEo[g] = make_float4(eo[a][0], eo[a][1], eo[a][2], eo[a][3]);
            *(float4*)&nJz[g] = make_float4(jz[a][0], jz[a][1], jz[a][2], jz[a][3]);
            *(float4*)&nJo[g] = make_float4(jo[a][0], jo[a][1], jo[a][2], jo[a][3]);
            *(float4*)&nHx[g] = make_float4(hx[a][0], hx[a][1], hx[a][2], hx[a][3]);
            *(float4*)&nHy[g] = make_float4(hy[a][0], hy[a][1], hy[a][2], hy[a][3]);
        }
    }
}

// ---------------------------------------------------------------------------
// Copy padded Ez -> dense 421x421 output.
// ---------------------------------------------------------------------------
__global__ void copy_out_kernel(const float* __restrict__ ezP,
                                float* __restrict__ out)
{
    int idx = blockIdx.x * blockDim.x + threadIdx.x;
    if (idx >= NXr * NXr) return;
    int gi = idx / NXr, gj = idx - gi * NXr;
    out[idx] = ezP[(gi + PAD) * PP + (gj + PAD)];
}

// ---------------------------------------------------------------------------
extern "C" void kernel_launch(void* const* d_in, const int* in_sizes, int n_in,
                              void* d_out, int out_size, void* d_ws, size_t ws_size,
                              hipStream_t stream)
{
    const float* src    = (const float*)d_in[0];
    const float* C1     = (const float*)d_in[1];
    const float* C2     = (const float*)d_in[2];
    const float* Cb_dx  = (const float*)d_in[3];
    const float* Cb_dy  = (const float*)d_in[4];
    const float* dbhx   = (const float*)d_in[5];
    const float* dbhy   = (const float*)d_in[6];
    const float* Ca     = (const float*)d_in[7];
    const float* Cb     = (const float*)d_in[8];
    const float* Cc     = (const float*)d_in[9];
    const float* Cd     = (const float*)d_in[10];
    const float* Ce     = (const float*)d_in[11];
    const float* sig_ex = (const float*)d_in[12];
    const float* sig_ey = (const float*)d_in[13];
    const float* sig_hx = (const float*)d_in[14];
    const float* sig_hy = (const float*)d_in[15];
    // d_in[16] = n_steps (always 200) — hard-coded for graph capture.

    const double EPS0 = 1e-9 / 36.0 / M_PI;
    const double MU0  = 4.0 * M_PI * 1e-7;
    const double C0   = 1.0 / sqrt(MU0 * EPS0);
    const double DXd  = 2.5e-8, DYd = 2.5e-8;
    const double DT   = 0.99 / C0 / sqrt(1.0 / (DXd * DXd) + 1.0 / (DYd * DYd));
    const float de_fac = (float)(DT / EPS0);
    const float dh_fac = (float)(DT / MU0);

    // Workspace: [guard row PP] [12 padded fields] [6 padded tables] (~11 MB)
    float* base = (float*)d_ws;
    float* fields = base + PP;
    float* w = fields + 12 * (size_t)FSZ;
    float* dexP = w; w += PP;
    float* deyP = w; w += PP;
    float* aexP = w; w += PP;
    float* aeyP = w; w += PP;
    float* ahxP = w; w += PP;
    float* ahyP = w; w += PP;

    PParams p;
    p.aEz = fields + 0 * (size_t)FSZ;  p.aEo = fields + 1 * (size_t)FSZ;
    p.aJz = fields + 2 * (size_t)FSZ;  p.aJo = fields + 3 * (size_t)FSZ;
    p.aHx = fields + 4 * (size_t)FSZ;  p.aHy = fields + 5 * (size_t)FSZ;
    p.bEz = fields + 6 * (size_t)FSZ;  p.bEo = fields + 7 * (size_t)FSZ;
    p.bJz = fields + 8 * (size_t)FSZ;  p.bJo = fields + 9 * (size_t)FSZ;
    p.bHx = fields + 10 * (size_t)FSZ; p.bHy = fields + 11 * (size_t)FSZ;
    p.dexP = dexP; p.deyP = deyP; p.aexP = aexP; p.aeyP = aeyP;
    p.ahxP = ahxP; p.ahyP = ahyP;
    p.C1a = C1; p.C2a = C2; p.Cbdxa = Cb_dx; p.Cbdya = Cb_dy;
    p.Caa = Ca; p.Cba = Cb; p.Cca = Cc; p.Cda = Cd; p.Cea = Ce;
    p.dbhxa = dbhx; p.dbhya = dbhy;
    p.src = src;

    init_kernel<<<512, 256, 0, stream>>>(sig_ex, sig_ey, sig_hx, sig_hy,
                                         de_fac, dh_fac,
                                         base, PP + 12 * FSZ,
                                         dexP, deyP, aexP, aeyP, ahxP, ahyP);

    dim3 blk(256);
    for (int t = 0; t < NPHASE; ++t) {
        int steps = (t < 12) ? 16 : 8;
        int n0 = 16 * t;
        // Support bound: after n steps the field is confined to a Chebyshev
        // ball of radius n-1 around the source. End of phase t (t<12) is step
        // 16(t+1) -> radius 16t+15; +8 slack -> R = 16t+23. Launch blocks
        // whose OWNED region [32b+16, 32b+48) intersects [CP-R, CP+R]
        // (conservative; extra blocks compute exact zeros; launch sets are
        // monotone in t so the ping-pong skip stays exact). Tail: full grid.
        // t-only formula -> identical grids every call (graph-capture safe).
        int R  = (t < 12) ? (16 * t + 23) : 1000;
        int lo = CP - R, hi = CP + R;
        int b0 = (lo - 47) / Bt; if (b0 < 0) b0 = 0;
        int b1 = (hi - 16) / Bt; if (b1 > NBLK - 1) b1 = NBLK - 1;
        dim3 g(b1 - b0 + 1, b1 - b0 + 1);
        phase_kernel<<<g, blk, 0, stream>>>(p, t, b0, steps, n0);
    }

    // 13 phases starting from set A: t=12 (even) reads A, writes B.
    copy_out_kernel<<<(NXr * NXr + 255) / 256, 256, 0, stream>>>(p.bEz,
                                                                 (float*)d_out);
}